// Round 3
// baseline (1715.332 us; speedup 1.0000x reference)
//
#include <hip/hip_runtime.h>

typedef __attribute__((ext_vector_type(8))) short bf16x8;
typedef __attribute__((ext_vector_type(4))) float f32x4;

#define NB 16384
#define NK 2048
#define ND 1000
#define NCH 64

__device__ float  g_dist[(size_t)NB * NK];   // 128 MiB, fully rewritten each call
__device__ float  g_u[NK], g_c2[NK], g_scnt[NK], g_Ak[NK];
__device__ float  g_v[NB], g_f2[NB], g_bd[NB];
__device__ double g_part[(size_t)NCH * NK];
__device__ int    g_cc[NK], g_rc[NK];

__device__ __forceinline__ ushort bf16_rne(float x){
    uint u = __float_as_uint(x);
    uint lsb = (u >> 16) & 1u;
    u += 0x7fffu + lsb;
    return (ushort)(u >> 16);
}
__device__ __forceinline__ float bf16_to_f(ushort h){
    return __uint_as_float(((uint)h) << 16);
}

// ---------------- row sum of squares (fp64 accumulate) ----------------
__global__ __launch_bounds__(256) void cn_rowsq(const float* __restrict__ X,
                                                int rows, int cols, int which){
    int wid = threadIdx.x >> 6, lane = threadIdx.x & 63;
    int row = blockIdx.x * 4 + wid;
    if (row >= rows) return;
    double acc = 0.0;
    for (int c = lane; c < cols; c += 64){
        float x = X[(size_t)row * cols + c];
        acc += (double)x * (double)x;
    }
    for (int off = 32; off; off >>= 1) acc += __shfl_xor(acc, off);
    if (lane == 0){
        if (which == 0) g_f2[row] = (float)acc;
        else            g_c2[row] = (float)acc;
    }
}

// ---------------- split-bf16 MFMA distance GEMM ----------------
// dist[b,k] = sqrt(max(f2[b] + c2[k] - 2*dot(F[b],C[k]), 0))
// dot via 3-term split: fh*ch + fh*cl + fl*ch  (~fp32 accuracy)
__global__ __launch_bounds__(256) void cn_gemm_dist(const float* __restrict__ F,
                                                    const float* __restrict__ Cn){
    __shared__ ushort Ah[128][40];
    __shared__ ushort Al[128][40];
    __shared__ ushort Bh[128][40];
    __shared__ ushort Bl[128][40];

    const int tid = threadIdx.x;
    const int lane = tid & 63, wid = tid >> 6;
    const int wr = wid >> 1, wc = wid & 1;
    const int brow0 = blockIdx.y * 128, bcol0 = blockIdx.x * 128;

    f32x4 acc[4][4];
#pragma unroll
    for (int m = 0; m < 4; ++m)
#pragma unroll
        for (int n = 0; n < 4; ++n) acc[m][n] = (f32x4){0.f,0.f,0.f,0.f};

    const int sr = tid >> 3;          // 0..31
    const int scol = (tid & 7) * 4;   // 0,4,...,28

    for (int step = 0; step < 32; ++step){
        const int k0 = step * 32;
        const bool inb = (k0 + scol + 4 <= ND);
#pragma unroll
        for (int j = 0; j < 4; ++j){
            int row = sr + 32 * j;
            float4 av = make_float4(0.f,0.f,0.f,0.f);
            float4 bv = make_float4(0.f,0.f,0.f,0.f);
            if (inb){
                av = *(const float4*)(F  + (size_t)(brow0 + row) * ND + k0 + scol);
                bv = *(const float4*)(Cn + (size_t)(bcol0 + row) * ND + k0 + scol);
            }
            ushort4 ah4, al4, bh4, bl4;
#pragma unroll
            for (int c = 0; c < 4; ++c){
                float xa = (&av.x)[c];
                ushort ha = bf16_rne(xa);
                ushort la = bf16_rne(xa - bf16_to_f(ha));
                (&ah4.x)[c] = ha; (&al4.x)[c] = la;
                float xb = (&bv.x)[c];
                ushort hb = bf16_rne(xb);
                ushort lb = bf16_rne(xb - bf16_to_f(hb));
                (&bh4.x)[c] = hb; (&bl4.x)[c] = lb;
            }
            *(ushort4*)&Ah[row][scol] = ah4;
            *(ushort4*)&Al[row][scol] = al4;
            *(ushort4*)&Bh[row][scol] = bh4;
            *(ushort4*)&Bl[row][scol] = bl4;
        }
        __syncthreads();

        const int arow = wr * 64 + (lane & 15);
        const int brow = wc * 64 + (lane & 15);
        const int kof  = (lane >> 4) * 8;
        bf16x8 afh[4], afl[4], bfh[4], bfl[4];
#pragma unroll
        for (int m = 0; m < 4; ++m){
            afh[m] = *(const bf16x8*)&Ah[arow + m * 16][kof];
            afl[m] = *(const bf16x8*)&Al[arow + m * 16][kof];
        }
#pragma unroll
        for (int n = 0; n < 4; ++n){
            bfh[n] = *(const bf16x8*)&Bh[brow + n * 16][kof];
            bfl[n] = *(const bf16x8*)&Bl[brow + n * 16][kof];
        }
#pragma unroll
        for (int m = 0; m < 4; ++m)
#pragma unroll
            for (int n = 0; n < 4; ++n){
                acc[m][n] = __builtin_amdgcn_mfma_f32_16x16x32_bf16(afh[m], bfh[n], acc[m][n], 0, 0, 0);
                acc[m][n] = __builtin_amdgcn_mfma_f32_16x16x32_bf16(afh[m], bfl[n], acc[m][n], 0, 0, 0);
                acc[m][n] = __builtin_amdgcn_mfma_f32_16x16x32_bf16(afl[m], bfh[n], acc[m][n], 0, 0, 0);
            }
        __syncthreads();
    }

#pragma unroll
    for (int m = 0; m < 4; ++m){
        int rowb = brow0 + wr * 64 + m * 16 + (lane >> 4) * 4;
#pragma unroll
        for (int n = 0; n < 4; ++n){
            int col = bcol0 + wc * 64 + n * 16 + (lane & 15);
            float c2v = g_c2[col];
#pragma unroll
            for (int j = 0; j < 4; ++j){
                float d2 = g_f2[rowb + j] + c2v - 2.0f * acc[m][n][j];
                g_dist[(size_t)(rowb + j) * NK + col] = sqrtf(fmaxf(d2, 0.0f));
            }
        }
    }
}

// ---------------- row pass: v_b = cst / sum_k exp(-2d) * (useW ? u_k : 1) ----------------
__global__ __launch_bounds__(256) void cn_row_pass(float cst, int useW){
    int wid = threadIdx.x >> 6, lane = threadIdx.x & 63;
    int b = blockIdx.x * 4 + wid;
    const float* dr = g_dist + (size_t)b * NK;
    double acc = 0.0;
#pragma unroll 4
    for (int i = 0; i < NK / 64; ++i){
        int k = i * 64 + lane;
        float e = __expf(-2.0f * dr[k]);
        if (useW) e *= g_u[k];
        acc += (double)e;
    }
    for (int off = 32; off; off >>= 1) acc += __shfl_xor(acc, off);
    if (lane == 0) g_v[b] = (float)((double)cst / acc);
}

// ---------------- col pass: per-k partial sums over a b-chunk of exp(-2d)*v (fp64) ----------------
__global__ __launch_bounds__(256) void cn_col_pass(){
    int k = blockIdx.x * 256 + threadIdx.x;
    int ch = blockIdx.y;
    const int BC = NB / NCH;   // 256 rows per chunk
    double acc = 0.0;
    for (int bb = 0; bb < BC; ++bb){
        int b = ch * BC + bb;
        float e = __expf(-2.0f * g_dist[(size_t)b * NK + k]);
        acc += (double)(e * g_v[b]);
    }
    g_part[(size_t)ch * NK + k] = acc;
}

// mode 0: u[k] = (1/K)/S_k      mode 1: scnt[k] = B*u[k]*S_k
__global__ __launch_bounds__(256) void cn_col_reduce(int mode){
    int k = blockIdx.x * 256 + threadIdx.x;
    double s = 0.0;
    for (int ch = 0; ch < NCH; ++ch) s += g_part[(size_t)ch * NK + k];
    if (mode == 0) g_u[k] = (float)((1.0 / (double)NK) / s);
    else           g_scnt[k] = (float)((double)NB * (double)g_u[k] * s);
}

__global__ __launch_bounds__(256) void cn_mk_ak(){
    int k = blockIdx.x * 256 + threadIdx.x;
    g_Ak[k] = (float)log((double)g_u[k] * (double)NK);
}

// ---------------- argmax(2d - Ak) [= argmin soft], argmin d, histograms ----------------
__global__ __launch_bounds__(256) void cn_assign(float* __restrict__ outba){
    int wid = threadIdx.x >> 6, lane = threadIdx.x & 63;
    int b = blockIdx.x * 4 + wid;
    const float* dr = g_dist + (size_t)b * NK;
    double bestT = -1.0e300; int bi = 0; float bd = 0.f;
    float rbest = 3.4e38f;   int ri = 0;
    for (int i = 0; i < NK / 64; ++i){
        int k = i * 64 + lane;
        float d = dr[k];
        double t = 2.0 * (double)d - (double)g_Ak[k];
        if (t > bestT){ bestT = t; bi = k; bd = d; }
        if (d < rbest){ rbest = d; ri = k; }
    }
    for (int off = 32; off; off >>= 1){
        double oT = __shfl_xor(bestT, off);
        int    oi = __shfl_xor(bi, off);
        float  od = __shfl_xor(bd, off);
        if (oT > bestT || (oT == bestT && oi < bi)){ bestT = oT; bi = oi; bd = od; }
        float orb = __shfl_xor(rbest, off);
        int   ori = __shfl_xor(ri, off);
        if (orb < rbest || (orb == rbest && ori < ri)){ rbest = orb; ri = ori; }
    }
    if (lane == 0){
        outba[b] = (float)bi;          // float32 output buffer
        g_bd[b] = bd;
        atomicAdd(&g_cc[bi], 1);
        atomicAdd(&g_rc[ri], 1);
    }
}

__global__ __launch_bounds__(256) void cn_zero(){
    int i = blockIdx.x * 256 + threadIdx.x;
    if (i < NK){ g_cc[i] = 0; g_rc[i] = 0; }
}

__global__ __launch_bounds__(256) void cn_finalize(float* __restrict__ out){
    int i = blockIdx.x * 256 + threadIdx.x;
    if (i < NK){
        out[1 + NB + i]            = g_scnt[i];
        out[1 + NB + NK + i]       = (float)g_cc[i];
        out[1 + NB + 2 * NK + i]   = (float)g_rc[i];
    }
    if (blockIdx.x == 0){
        // deterministic fp64 loss reduction: fixed per-thread strided sums + fixed tree
        __shared__ double red[4];
        int lane = threadIdx.x & 63, wid = threadIdx.x >> 6;
        double s = 0.0;
        for (int b = threadIdx.x; b < NB; b += 256) s += (double)g_bd[b];
        for (int off = 32; off; off >>= 1) s += __shfl_xor(s, off);
        if (lane == 0) red[wid] = s;
        __syncthreads();
        if (threadIdx.x == 0){
            double tot = red[0] + red[1] + red[2] + red[3];
            out[0] = (float)(tot / (double)NB);
        }
    }
}

extern "C" void kernel_launch(void* const* d_in, const int* in_sizes, int n_in,
                              void* d_out, int out_size, void* d_ws, size_t ws_size,
                              hipStream_t stream){
    const float* F  = (const float*)d_in[0];
    const float* Cn = (const float*)d_in[1];
    float* out = (float*)d_out;
    (void)d_ws; (void)ws_size;

    cn_rowsq<<<NB / 4, 256, 0, stream>>>(F, NB, ND, 0);
    cn_rowsq<<<NK / 4, 256, 0, stream>>>(Cn, NK, ND, 1);
    cn_zero<<<NK / 256, 256, 0, stream>>>();

    dim3 gg(NK / 128, NB / 128);
    cn_gemm_dist<<<gg, 256, 0, stream>>>(F, Cn);

    // v0 = 1 / colsum(K0)  (initial Q normalization; Q is [K,B])
    cn_row_pass<<<NB / 4, 256, 0, stream>>>(1.0f, 0);

    for (int it = 0; it < 15; ++it){
        cn_col_pass<<<dim3(NK / 256, NCH), 256, 0, stream>>>();
        cn_col_reduce<<<NK / 256, 256, 0, stream>>>(0);
        cn_row_pass<<<NB / 4, 256, 0, stream>>>(1.0f / (float)NB, 1);
    }

    // soft_counts = B * u ⊙ (K0 v_final)
    cn_col_pass<<<dim3(NK / 256, NCH), 256, 0, stream>>>();
    cn_col_reduce<<<NK / 256, 256, 0, stream>>>(1);

    cn_mk_ak<<<NK / 256, 256, 0, stream>>>();
    cn_assign<<<NB / 4, 256, 0, stream>>>(out + 1);
    cn_finalize<<<NK / 256, 256, 0, stream>>>(out);
}

// Round 4
// 1108.982 us; speedup vs baseline: 1.5468x; 1.5468x over previous
//
#include <hip/hip_runtime.h>

typedef __attribute__((ext_vector_type(8))) short bf16x8;
typedef __attribute__((ext_vector_type(4))) float f32x4;

#define NB 16384
#define NK 2048
#define ND 1000
#define NWCH 4096          // wave-chunks: 4 rows per wave

__device__ float  g_dist[(size_t)NB * NK];      // 128 MiB
__device__ float  g_u[NK], g_c2[NK], g_scnt[NK];
__device__ float  g_f2[NB], g_bd[NB];
__device__ float  g_part[(size_t)NWCH * NK];    // 32 MiB fp32 partials
__device__ double g_part2[16 * NK];
__device__ int    g_cc[NK], g_rc[NK];

__device__ __forceinline__ ushort bf16_rne(float x){
    uint u = __float_as_uint(x);
    uint lsb = (u >> 16) & 1u;
    u += 0x7fffu + lsb;
    return (ushort)(u >> 16);
}
__device__ __forceinline__ float bf16_to_f(ushort h){
    return __uint_as_float(((uint)h) << 16);
}

// ---------------- row sum of squares (fp64 accumulate) ----------------
__global__ __launch_bounds__(256) void cn_rowsq(const float* __restrict__ X,
                                                int rows, int cols, int which){
    int wid = threadIdx.x >> 6, lane = threadIdx.x & 63;
    int row = blockIdx.x * 4 + wid;
    if (row >= rows) return;
    double acc = 0.0;
    for (int c = lane; c < cols; c += 64){
        float x = X[(size_t)row * cols + c];
        acc += (double)x * (double)x;
    }
    for (int off = 32; off; off >>= 1) acc += __shfl_xor(acc, off);
    if (lane == 0){
        if (which == 0) g_f2[row] = (float)acc;
        else            g_c2[row] = (float)acc;
    }
}

// ---------------- split-bf16 MFMA distance GEMM (unchanged, verified) ----------------
__global__ __launch_bounds__(256) void cn_gemm_dist(const float* __restrict__ F,
                                                    const float* __restrict__ Cn){
    __shared__ ushort Ah[128][40];
    __shared__ ushort Al[128][40];
    __shared__ ushort Bh[128][40];
    __shared__ ushort Bl[128][40];

    const int tid = threadIdx.x;
    const int lane = tid & 63, wid = tid >> 6;
    const int wr = wid >> 1, wc = wid & 1;
    const int brow0 = blockIdx.y * 128, bcol0 = blockIdx.x * 128;

    f32x4 acc[4][4];
#pragma unroll
    for (int m = 0; m < 4; ++m)
#pragma unroll
        for (int n = 0; n < 4; ++n) acc[m][n] = (f32x4){0.f,0.f,0.f,0.f};

    const int sr = tid >> 3;
    const int scol = (tid & 7) * 4;

    for (int step = 0; step < 32; ++step){
        const int k0 = step * 32;
        const bool inb = (k0 + scol + 4 <= ND);
#pragma unroll
        for (int j = 0; j < 4; ++j){
            int row = sr + 32 * j;
            float4 av = make_float4(0.f,0.f,0.f,0.f);
            float4 bv = make_float4(0.f,0.f,0.f,0.f);
            if (inb){
                av = *(const float4*)(F  + (size_t)(brow0 + row) * ND + k0 + scol);
                bv = *(const float4*)(Cn + (size_t)(bcol0 + row) * ND + k0 + scol);
            }
            ushort4 ah4, al4, bh4, bl4;
#pragma unroll
            for (int c = 0; c < 4; ++c){
                float xa = (&av.x)[c];
                ushort ha = bf16_rne(xa);
                ushort la = bf16_rne(xa - bf16_to_f(ha));
                (&ah4.x)[c] = ha; (&al4.x)[c] = la;
                float xb = (&bv.x)[c];
                ushort hb = bf16_rne(xb);
                ushort lb = bf16_rne(xb - bf16_to_f(hb));
                (&bh4.x)[c] = hb; (&bl4.x)[c] = lb;
            }
            *(ushort4*)&Ah[row][scol] = ah4;
            *(ushort4*)&Al[row][scol] = al4;
            *(ushort4*)&Bh[row][scol] = bh4;
            *(ushort4*)&Bl[row][scol] = bl4;
        }
        __syncthreads();

        const int arow = wr * 64 + (lane & 15);
        const int brow = wc * 64 + (lane & 15);
        const int kof  = (lane >> 4) * 8;
        bf16x8 afh[4], afl[4], bfh[4], bfl[4];
#pragma unroll
        for (int m = 0; m < 4; ++m){
            afh[m] = *(const bf16x8*)&Ah[arow + m * 16][kof];
            afl[m] = *(const bf16x8*)&Al[arow + m * 16][kof];
        }
#pragma unroll
        for (int n = 0; n < 4; ++n){
            bfh[n] = *(const bf16x8*)&Bh[brow + n * 16][kof];
            bfl[n] = *(const bf16x8*)&Bl[brow + n * 16][kof];
        }
#pragma unroll
        for (int m = 0; m < 4; ++m)
#pragma unroll
            for (int n = 0; n < 4; ++n){
                acc[m][n] = __builtin_amdgcn_mfma_f32_16x16x32_bf16(afh[m], bfh[n], acc[m][n], 0, 0, 0);
                acc[m][n] = __builtin_amdgcn_mfma_f32_16x16x32_bf16(afh[m], bfl[n], acc[m][n], 0, 0, 0);
                acc[m][n] = __builtin_amdgcn_mfma_f32_16x16x32_bf16(afl[m], bfh[n], acc[m][n], 0, 0, 0);
            }
        __syncthreads();
    }

#pragma unroll
    for (int m = 0; m < 4; ++m){
        int rowb = brow0 + wr * 64 + m * 16 + (lane >> 4) * 4;
#pragma unroll
        for (int n = 0; n < 4; ++n){
            int col = bcol0 + wc * 64 + n * 16 + (lane & 15);
            float c2v = g_c2[col];
#pragma unroll
            for (int j = 0; j < 4; ++j){
                float d2 = g_f2[rowb + j] + c2v - 2.0f * acc[m][n][j];
                g_dist[(size_t)(rowb + j) * NK + col] = sqrtf(fmaxf(d2, 0.0f));
            }
        }
    }
}

// ---------------- fused sinkhorn sweep ----------------
// MODE 0: first sweep (u implicit = 1):  v_b = 1/T_b,    S += e*v
// MODE 1: mid sweep:                     v_b = (1/B)/T_b, S += e*v   (T = sum e*u)
// MODE 2: final: same as 1, plus argmax(2d - ln(uK)), argmin d, bd, histograms
// Each wave handles 4 rows; lane's 32 k-slots: k = 4*lane + 256*j + c.
template<int MODE>
__global__ __launch_bounds__(256) void cn_sweep(float* __restrict__ outba){
    const int lane = threadIdx.x & 63, wid = threadIdx.x >> 6;
    const int wchunk = blockIdx.x * 4 + wid;    // 0..4095
    const int row0 = wchunk * 4;
    const float cst = (MODE == 0) ? 1.0f : (1.0f / (float)NB);

    float4 uu[8];
    float4 ak[8];
    if (MODE >= 1){
#pragma unroll
        for (int j = 0; j < 8; ++j)
            uu[j] = *(const float4*)&g_u[4 * lane + 256 * j];
    }
    if (MODE == 2){
#pragma unroll
        for (int j = 0; j < 8; ++j)
#pragma unroll
            for (int c = 0; c < 4; ++c)
                (&ak[j].x)[c] = (float)log((double)(&uu[j].x)[c] * (double)NK);
    }

    float4 S[8];
#pragma unroll
    for (int j = 0; j < 8; ++j) S[j] = make_float4(0.f,0.f,0.f,0.f);

    for (int r = 0; r < 4; ++r){
        const int b = row0 + r;
        const float* dr = g_dist + (size_t)b * NK + 4 * lane;
        float4 ev[8];
        float4 dv[8];
        float tsum = 0.f;
#pragma unroll
        for (int j = 0; j < 8; ++j){
            float4 d4 = *(const float4*)(dr + 256 * j);
            float4 e4;
#pragma unroll
            for (int c = 0; c < 4; ++c){
                float e = __expf(-2.0f * (&d4.x)[c]);
                (&e4.x)[c] = e;
                tsum += (MODE >= 1) ? e * (&uu[j].x)[c] : e;
            }
            ev[j] = e4;
            if (MODE == 2) dv[j] = d4;
        }
#pragma unroll
        for (int off = 32; off; off >>= 1) tsum += __shfl_xor(tsum, off);
        const float v = cst / tsum;
#pragma unroll
        for (int j = 0; j < 8; ++j){
#pragma unroll
            for (int c = 0; c < 4; ++c)
                (&S[j].x)[c] += (&ev[j].x)[c] * v;
        }

        if (MODE == 2){
            double bestT = -1.0e300; int bi = 0; float bd = 0.f;
            float rbest = 3.4e38f;   int ri = 0;
#pragma unroll
            for (int j = 0; j < 8; ++j){
#pragma unroll
                for (int c = 0; c < 4; ++c){
                    int k = 256 * j + 4 * lane + c;
                    float d = (&dv[j].x)[c];
                    double t = 2.0 * (double)d - (double)(&ak[j].x)[c];
                    if (t > bestT){ bestT = t; bi = k; bd = d; }
                    if (d < rbest){ rbest = d; ri = k; }
                }
            }
            for (int off = 32; off; off >>= 1){
                double oT = __shfl_xor(bestT, off);
                int    oi = __shfl_xor(bi, off);
                float  od = __shfl_xor(bd, off);
                if (oT > bestT || (oT == bestT && oi < bi)){ bestT = oT; bi = oi; bd = od; }
                float orb = __shfl_xor(rbest, off);
                int   ori = __shfl_xor(ri, off);
                if (orb < rbest || (orb == rbest && ori < ri)){ rbest = orb; ri = ori; }
            }
            if (lane == 0){
                outba[b] = (float)bi;
                g_bd[b] = bd;
                atomicAdd(&g_cc[bi], 1);
                atomicAdd(&g_rc[ri], 1);
            }
        }
    }

#pragma unroll
    for (int j = 0; j < 8; ++j)
        *(float4*)&g_part[(size_t)wchunk * NK + 4 * lane + 256 * j] = S[j];
}

// ---------------- 2-stage partial reduction ----------------
__global__ __launch_bounds__(256) void cn_red1(){
    int k = blockIdx.x * 256 + threadIdx.x;
    int c0 = blockIdx.y * 256;
    double s = 0.0;
    for (int ch = 0; ch < 256; ++ch)
        s += (double)g_part[(size_t)(c0 + ch) * NK + k];
    g_part2[blockIdx.y * NK + k] = s;
}

// mode 0: u[k] = (1/K)/S_k      mode 1: scnt[k] = B*u[k]*S_k
__global__ __launch_bounds__(256) void cn_red2(int mode){
    int k = blockIdx.x * 256 + threadIdx.x;
    double s = 0.0;
    for (int i = 0; i < 16; ++i) s += g_part2[i * NK + k];
    if (mode == 0) g_u[k] = (float)((1.0 / (double)NK) / s);
    else           g_scnt[k] = (float)((double)NB * (double)g_u[k] * s);
}

__global__ __launch_bounds__(256) void cn_zero(){
    int i = blockIdx.x * 256 + threadIdx.x;
    if (i < NK){ g_cc[i] = 0; g_rc[i] = 0; }
}

__global__ __launch_bounds__(256) void cn_finalize(float* __restrict__ out){
    int i = blockIdx.x * 256 + threadIdx.x;
    if (i < NK){
        out[1 + NB + i]            = g_scnt[i];
        out[1 + NB + NK + i]       = (float)g_cc[i];
        out[1 + NB + 2 * NK + i]   = (float)g_rc[i];
    }
    if (blockIdx.x == 0){
        __shared__ double red[4];
        int lane = threadIdx.x & 63, wid = threadIdx.x >> 6;
        double s = 0.0;
        for (int b = threadIdx.x; b < NB; b += 256) s += (double)g_bd[b];
        for (int off = 32; off; off >>= 1) s += __shfl_xor(s, off);
        if (lane == 0) red[wid] = s;
        __syncthreads();
        if (threadIdx.x == 0){
            double tot = red[0] + red[1] + red[2] + red[3];
            out[0] = (float)(tot / (double)NB);
        }
    }
}

extern "C" void kernel_launch(void* const* d_in, const int* in_sizes, int n_in,
                              void* d_out, int out_size, void* d_ws, size_t ws_size,
                              hipStream_t stream){
    const float* F  = (const float*)d_in[0];
    const float* Cn = (const float*)d_in[1];
    float* out = (float*)d_out;
    (void)d_ws; (void)ws_size;

    cn_rowsq<<<NB / 4, 256, 0, stream>>>(F, NB, ND, 0);
    cn_rowsq<<<NK / 4, 256, 0, stream>>>(Cn, NK, ND, 1);
    cn_zero<<<NK / 256, 256, 0, stream>>>();

    dim3 gg(NK / 128, NB / 128);
    cn_gemm_dist<<<gg, 256, 0, stream>>>(F, Cn);

    dim3 r1(NK / 256, 16);

    // sweep 0: v0 = 1/rowsumE, accumulate S(v0) -> u_1
    cn_sweep<0><<<NWCH / 4, 256, 0, stream>>>(nullptr);
    cn_red1<<<r1, 256, 0, stream>>>();
    cn_red2<<<NK / 256, 256, 0, stream>>>(0);

    // sweeps 1..14: v_i from u_i, accumulate S(v_i) -> u_{i+1}
    for (int it = 1; it <= 14; ++it){
        cn_sweep<1><<<NWCH / 4, 256, 0, stream>>>(nullptr);
        cn_red1<<<r1, 256, 0, stream>>>();
        cn_red2<<<NK / 256, 256, 0, stream>>>(0);
    }

    // final sweep: v_15 from u_15, S(v_15) -> scnt; fused assign/argmin/loss
    cn_sweep<2><<<NWCH / 4, 256, 0, stream>>>(out + 1);
    cn_red1<<<r1, 256, 0, stream>>>();
    cn_red2<<<NK / 256, 256, 0, stream>>>(1);

    cn_finalize<<<NK / 256, 256, 0, stream>>>(out);
}

// Round 5
// 786.699 us; speedup vs baseline: 2.1804x; 1.4097x over previous
//
#include <hip/hip_runtime.h>

typedef __attribute__((ext_vector_type(8))) short bf16x8;
typedef __attribute__((ext_vector_type(4))) float f32x4;

#define NB 16384
#define NK 2048
#define ND 1000
#define KP 1024            // padded K
#define NCHK 1024          // sinkhorn partial chunks (1 per block)

__device__ float  g_dist[(size_t)NB * NK];          // 128 MiB
__device__ ushort g_Fh[(size_t)NB * KP], g_Fl[(size_t)NB * KP];   // 32+32 MiB
__device__ ushort g_Ch[(size_t)NK * KP], g_Cl[(size_t)NK * KP];   // 4+4 MiB
__device__ float  g_u[NK], g_c2[NK], g_scnt[NK];
__device__ float  g_f2[NB], g_bd[NB];
__device__ float  g_part[(size_t)NCHK * NK];        // 8 MiB
__device__ double g_part2[16 * NK];
__device__ int    g_cc[NK], g_rc[NK];

typedef const __attribute__((address_space(1))) void gvoid_t;
typedef __attribute__((address_space(3))) void lvoid_t;

__device__ __forceinline__ ushort bf16_rne(float x){
    uint u = __float_as_uint(x);
    uint lsb = (u >> 16) & 1u;
    u += 0x7fffu + lsb;
    return (ushort)(u >> 16);
}
__device__ __forceinline__ float bf16_to_f(ushort h){
    return __uint_as_float(((uint)h) << 16);
}

// ---------------- prep: fp32 -> (hi,lo) bf16 split, K-pad, fused row-sumsq ----------------
// one block per row; thread t handles cols 4t..4t+3 (250 float4 loads + pad)
__global__ __launch_bounds__(256) void cn_prep(const float* __restrict__ X,
                                               ushort* __restrict__ H,
                                               ushort* __restrict__ L,
                                               float* __restrict__ sq){
    const int row = blockIdx.x, t = threadIdx.x;
    const int lane = t & 63, wid = t >> 6;
    float4 x = make_float4(0.f,0.f,0.f,0.f);
    if (t < 250) x = *(const float4*)(X + (size_t)row * ND + 4 * t);
    double s = (double)x.x*x.x + (double)x.y*x.y + (double)x.z*x.z + (double)x.w*x.w;
    ushort4 h4, l4;
#pragma unroll
    for (int c = 0; c < 4; ++c){
        float xc = (&x.x)[c];
        ushort h = bf16_rne(xc);
        (&h4.x)[c] = h;
        (&l4.x)[c] = bf16_rne(xc - bf16_to_f(h));
    }
    *(ushort4*)&H[(size_t)row * KP + 4 * t] = h4;
    *(ushort4*)&L[(size_t)row * KP + 4 * t] = l4;

    __shared__ double pr[4];
    for (int off = 32; off; off >>= 1) s += __shfl_xor(s, off);
    if (lane == 0) pr[wid] = s;
    __syncthreads();
    if (t == 0) sq[row] = (float)(pr[0] + pr[1] + pr[2] + pr[3]);
}

// ---------------- split-bf16 MFMA distance GEMM, global_load_lds staging ----------------
__global__ __launch_bounds__(256) void cn_gemm_dist(){
    __shared__ __attribute__((aligned(16))) ushort Ah[128 * 32];
    __shared__ __attribute__((aligned(16))) ushort Al[128 * 32];
    __shared__ __attribute__((aligned(16))) ushort Bh[128 * 32];
    __shared__ __attribute__((aligned(16))) ushort Bl[128 * 32];

    const int tid = threadIdx.x;
    const int lane = tid & 63, wid = tid >> 6;
    const int wr = wid >> 1, wc = wid & 1;
    const int brow0 = blockIdx.y * 128, bcol0 = blockIdx.x * 128;

    f32x4 acc[4][4];
#pragma unroll
    for (int m = 0; m < 4; ++m)
#pragma unroll
        for (int n = 0; n < 4; ++n) acc[m][n] = (f32x4){0.f,0.f,0.f,0.f};

    // staging geometry: tile [128 rows][32 k] bf16 linear (64 B/row), 8 KB;
    // 8 wave-chunks of 1 KB (16 rows); wave w stages chunks 2w, 2w+1 of each tile.
    const int lrow = lane >> 2;            // 0..15 within chunk
    const int lcol = (lane & 3) * 8;       // ushort offset within row (16 B granules)

    for (int step = 0; step < 32; ++step){
        const int k0 = step * 32;
#pragma unroll
        for (int i = 0; i < 2; ++i){
            const int ch = wid * 2 + i;
            const int ldso = ch * 512;             // ushort offset (1 KB per chunk)
            const size_t ga = ((size_t)(brow0 + ch * 16 + lrow)) * KP + k0 + lcol;
            const size_t gb = ((size_t)(bcol0 + ch * 16 + lrow)) * KP + k0 + lcol;
            __builtin_amdgcn_global_load_lds((gvoid_t*)(g_Fh + ga), (lvoid_t*)(Ah + ldso), 16, 0, 0);
            __builtin_amdgcn_global_load_lds((gvoid_t*)(g_Fl + ga), (lvoid_t*)(Al + ldso), 16, 0, 0);
            __builtin_amdgcn_global_load_lds((gvoid_t*)(g_Ch + gb), (lvoid_t*)(Bh + ldso), 16, 0, 0);
            __builtin_amdgcn_global_load_lds((gvoid_t*)(g_Cl + gb), (lvoid_t*)(Bl + ldso), 16, 0, 0);
        }
        __syncthreads();

        const int arow = wr * 64 + (lane & 15);
        const int brow = wc * 64 + (lane & 15);
        const int kof  = (lane >> 4) * 8;
        bf16x8 afh[4], afl[4], bfh[4], bfl[4];
#pragma unroll
        for (int m = 0; m < 4; ++m){
            afh[m] = *(const bf16x8*)&Ah[(arow + m * 16) * 32 + kof];
            afl[m] = *(const bf16x8*)&Al[(arow + m * 16) * 32 + kof];
        }
#pragma unroll
        for (int n = 0; n < 4; ++n){
            bfh[n] = *(const bf16x8*)&Bh[(brow + n * 16) * 32 + kof];
            bfl[n] = *(const bf16x8*)&Bl[(brow + n * 16) * 32 + kof];
        }
#pragma unroll
        for (int m = 0; m < 4; ++m)
#pragma unroll
            for (int n = 0; n < 4; ++n){
                acc[m][n] = __builtin_amdgcn_mfma_f32_16x16x32_bf16(afh[m], bfh[n], acc[m][n], 0, 0, 0);
                acc[m][n] = __builtin_amdgcn_mfma_f32_16x16x32_bf16(afh[m], bfl[n], acc[m][n], 0, 0, 0);
                acc[m][n] = __builtin_amdgcn_mfma_f32_16x16x32_bf16(afl[m], bfh[n], acc[m][n], 0, 0, 0);
            }
        __syncthreads();
    }

#pragma unroll
    for (int m = 0; m < 4; ++m){
        int rowb = brow0 + wr * 64 + m * 16 + (lane >> 4) * 4;
#pragma unroll
        for (int n = 0; n < 4; ++n){
            int col = bcol0 + wc * 64 + n * 16 + (lane & 15);
            float c2v = g_c2[col];
#pragma unroll
            for (int j = 0; j < 4; ++j){
                float d2 = g_f2[rowb + j] + c2v - 2.0f * acc[m][n][j];
                g_dist[(size_t)(rowb + j) * NK + col] = sqrtf(fmaxf(d2, 0.0f));
            }
        }
    }
}

// ---------------- fused sinkhorn sweep (+ in-block partial reduction) ----------------
// MODE 0: v_b = 1/T_b (u==1);  MODE 1: v_b = (1/B)/T_b, T = sum e*u
// MODE 2: MODE1 + argmax(2d - ln(uK)), argmin d, bd, histograms
// wave handles 4 rows; lane k-slots: k = 4*lane + 256*j + c. Block = 16 rows.
template<int MODE>
__global__ __launch_bounds__(256) void cn_sweep(float* __restrict__ outba){
    __shared__ float4 sred[3][8][64];
    const int lane = threadIdx.x & 63, wid = threadIdx.x >> 6;
    const int row0 = (blockIdx.x * 4 + wid) * 4;
    const float cst = (MODE == 0) ? 1.0f : (1.0f / (float)NB);

    float4 uu[8];
    float4 ak[8];
    if (MODE >= 1){
#pragma unroll
        for (int j = 0; j < 8; ++j)
            uu[j] = *(const float4*)&g_u[4 * lane + 256 * j];
    }
    if (MODE == 2){
#pragma unroll
        for (int j = 0; j < 8; ++j)
#pragma unroll
            for (int c = 0; c < 4; ++c)
                (&ak[j].x)[c] = (float)log((double)(&uu[j].x)[c] * (double)NK);
    }

    float4 S[8];
#pragma unroll
    for (int j = 0; j < 8; ++j) S[j] = make_float4(0.f,0.f,0.f,0.f);

    for (int r = 0; r < 4; ++r){
        const int b = row0 + r;
        const float* dr = g_dist + (size_t)b * NK + 4 * lane;
        float4 ev[8];
        float4 dv[8];
        float tsum = 0.f;
#pragma unroll
        for (int j = 0; j < 8; ++j){
            float4 d4 = *(const float4*)(dr + 256 * j);
            float4 e4;
#pragma unroll
            for (int c = 0; c < 4; ++c){
                float e = __expf(-2.0f * (&d4.x)[c]);
                (&e4.x)[c] = e;
                tsum += (MODE >= 1) ? e * (&uu[j].x)[c] : e;
            }
            ev[j] = e4;
            if (MODE == 2) dv[j] = d4;
        }
#pragma unroll
        for (int off = 32; off; off >>= 1) tsum += __shfl_xor(tsum, off);
        const float v = cst / tsum;
#pragma unroll
        for (int j = 0; j < 8; ++j){
#pragma unroll
            for (int c = 0; c < 4; ++c)
                (&S[j].x)[c] += (&ev[j].x)[c] * v;
        }

        if (MODE == 2){
            double bestT = -1.0e300; int bi = 0; float bd = 0.f;
            float rbest = 3.4e38f;   int ri = 0;
#pragma unroll
            for (int j = 0; j < 8; ++j){
#pragma unroll
                for (int c = 0; c < 4; ++c){
                    int k = 256 * j + 4 * lane + c;
                    float d = (&dv[j].x)[c];
                    double t = 2.0 * (double)d - (double)(&ak[j].x)[c];
                    if (t > bestT){ bestT = t; bi = k; bd = d; }
                    if (d < rbest){ rbest = d; ri = k; }
                }
            }
            for (int off = 32; off; off >>= 1){
                double oT = __shfl_xor(bestT, off);
                int    oi = __shfl_xor(bi, off);
                float  od = __shfl_xor(bd, off);
                if (oT > bestT || (oT == bestT && oi < bi)){ bestT = oT; bi = oi; bd = od; }
                float orb = __shfl_xor(rbest, off);
                int   ori = __shfl_xor(ri, off);
                if (orb < rbest || (orb == rbest && ori < ri)){ rbest = orb; ri = ori; }
            }
            if (lane == 0){
                outba[b] = (float)bi;
                g_bd[b] = bd;
                atomicAdd(&g_cc[bi], 1);
                atomicAdd(&g_rc[ri], 1);
            }
        }
    }

    // in-block cross-wave reduction of S (conflict-free [w][j][lane] layout)
    if (wid > 0){
#pragma unroll
        for (int j = 0; j < 8; ++j) sred[wid - 1][j][lane] = S[j];
    }
    __syncthreads();
    if (wid == 0){
#pragma unroll
        for (int w = 0; w < 3; ++w)
#pragma unroll
            for (int j = 0; j < 8; ++j){
                float4 o = sred[w][j][lane];
                S[j].x += o.x; S[j].y += o.y; S[j].z += o.z; S[j].w += o.w;
            }
#pragma unroll
        for (int j = 0; j < 8; ++j)
            *(float4*)&g_part[(size_t)blockIdx.x * NK + 4 * lane + 256 * j] = S[j];
    }
}

// ---------------- 2-stage partial reduction ----------------
__global__ __launch_bounds__(256) void cn_red1(){
    int k = blockIdx.x * 256 + threadIdx.x;
    int c0 = blockIdx.y * 64;
    double s = 0.0;
    for (int ch = 0; ch < 64; ++ch)
        s += (double)g_part[(size_t)(c0 + ch) * NK + k];
    g_part2[blockIdx.y * NK + k] = s;
}

// mode 0: u[k] = (1/K)/S_k      mode 1: scnt[k] = B*u[k]*S_k
__global__ __launch_bounds__(256) void cn_red2(int mode){
    int k = blockIdx.x * 256 + threadIdx.x;
    double s = 0.0;
    for (int i = 0; i < 16; ++i) s += g_part2[i * NK + k];
    if (mode == 0) g_u[k] = (float)((1.0 / (double)NK) / s);
    else           g_scnt[k] = (float)((double)NB * (double)g_u[k] * s);
}

__global__ __launch_bounds__(256) void cn_zero(){
    int i = blockIdx.x * 256 + threadIdx.x;
    if (i < NK){ g_cc[i] = 0; g_rc[i] = 0; }
}

__global__ __launch_bounds__(256) void cn_finalize(float* __restrict__ out){
    int i = blockIdx.x * 256 + threadIdx.x;
    if (i < NK){
        out[1 + NB + i]            = g_scnt[i];
        out[1 + NB + NK + i]       = (float)g_cc[i];
        out[1 + NB + 2 * NK + i]   = (float)g_rc[i];
    }
    if (blockIdx.x == 0){
        __shared__ double red[4];
        int lane = threadIdx.x & 63, wid = threadIdx.x >> 6;
        double s = 0.0;
        for (int b = threadIdx.x; b < NB; b += 256) s += (double)g_bd[b];
        for (int off = 32; off; off >>= 1) s += __shfl_xor(s, off);
        if (lane == 0) red[wid] = s;
        __syncthreads();
        if (threadIdx.x == 0){
            double tot = red[0] + red[1] + red[2] + red[3];
            out[0] = (float)(tot / (double)NB);
        }
    }
}

extern "C" void kernel_launch(void* const* d_in, const int* in_sizes, int n_in,
                              void* d_out, int out_size, void* d_ws, size_t ws_size,
                              hipStream_t stream){
    const float* F  = (const float*)d_in[0];
    const float* Cn = (const float*)d_in[1];
    float* out = (float*)d_out;
    (void)d_ws; (void)ws_size;

    // hi/lo split + padded layout + fused row-sumsq
    {
        ushort *fh, *fl, *ch, *cl; float *f2, *c2;
        hipGetSymbolAddress((void**)&fh, HIP_SYMBOL(g_Fh));
        hipGetSymbolAddress((void**)&fl, HIP_SYMBOL(g_Fl));
        hipGetSymbolAddress((void**)&ch, HIP_SYMBOL(g_Ch));
        hipGetSymbolAddress((void**)&cl, HIP_SYMBOL(g_Cl));
        hipGetSymbolAddress((void**)&f2, HIP_SYMBOL(g_f2));
        hipGetSymbolAddress((void**)&c2, HIP_SYMBOL(g_c2));
        cn_prep<<<NB, 256, 0, stream>>>(F, fh, fl, f2);
        cn_prep<<<NK, 256, 0, stream>>>(Cn, ch, cl, c2);
    }
    cn_zero<<<NK / 256, 256, 0, stream>>>();

    dim3 gg(NK / 128, NB / 128);
    cn_gemm_dist<<<gg, 256, 0, stream>>>();

    dim3 r1(NK / 256, 16);

    // sweep 0: v0 = 1/rowsumE, accumulate S(v0) -> u_1
    cn_sweep<0><<<NCHK, 256, 0, stream>>>(nullptr);
    cn_red1<<<r1, 256, 0, stream>>>();
    cn_red2<<<NK / 256, 256, 0, stream>>>(0);

    for (int it = 1; it <= 14; ++it){
        cn_sweep<1><<<NCHK, 256, 0, stream>>>(nullptr);
        cn_red1<<<r1, 256, 0, stream>>>();
        cn_red2<<<NK / 256, 256, 0, stream>>>(0);
    }

    // final sweep: fused assign/argmin/loss; S(v_15) -> scnt
    cn_sweep<2><<<NCHK, 256, 0, stream>>>(out + 1);
    cn_red1<<<r1, 256, 0, stream>>>();
    cn_red2<<<NK / 256, 256, 0, stream>>>(1);

    cn_finalize<<<NK / 256, 256, 0, stream>>>(out);
}

// Round 6
// 775.530 us; speedup vs baseline: 2.2118x; 1.0144x over previous
//
#include <hip/hip_runtime.h>

typedef __attribute__((ext_vector_type(8))) short bf16x8;
typedef __attribute__((ext_vector_type(4))) float f32x4;

#define NB 16384
#define NK 2048
#define ND 1000
#define KP 1024            // padded K
#define NCHK 1024          // sinkhorn partial chunks (1 per sweep block)

__device__ float  g_dist[(size_t)NB * NK];          // 128 MiB
__device__ ushort g_E[(size_t)NB * NK];             // 64 MiB fp16 e' = exp(-2d)*8192
__device__ ushort g_Fh[(size_t)NB * KP], g_Fl[(size_t)NB * KP];   // 32+32 MiB (pre-swizzled)
__device__ ushort g_Ch[(size_t)NK * KP], g_Cl[(size_t)NK * KP];   // 4+4 MiB (pre-swizzled)
__device__ float  g_u[NK], g_c2[NK], g_scnt[NK];
__device__ float  g_f2[NB], g_bd[NB];
__device__ float  g_part[(size_t)NCHK * NK];        // 8 MiB
__device__ int    g_cc[NK], g_rc[NK];

typedef const __attribute__((address_space(1))) void gvoid_t;
typedef __attribute__((address_space(3))) void lvoid_t;

union h16 { ushort u; _Float16 h; };

__device__ __forceinline__ ushort bf16_rne(float x){
    uint u = __float_as_uint(x);
    uint lsb = (u >> 16) & 1u;
    u += 0x7fffu + lsb;
    return (ushort)(u >> 16);
}
__device__ __forceinline__ float bf16_to_f(ushort h){
    return __uint_as_float(((uint)h) << 16);
}

// ---------------- prep: fp32 -> (hi,lo) bf16 split, K-pad, XOR-swizzled layout,
// fused row-sumsq. Swizzle: within each 32-col window, 8-elem group g stored at
// g ^ ((row>>1)&3)  -> GEMM ds_read_b128 becomes 2-way-per-bank (free).
template<int WHICH>
__global__ __launch_bounds__(256) void cn_prep(const float* __restrict__ X){
    ushort* __restrict__ H = WHICH ? g_Ch : g_Fh;
    ushort* __restrict__ L = WHICH ? g_Cl : g_Fl;
    float*  __restrict__ sq = WHICH ? g_c2 : g_f2;
    const int row = blockIdx.x, t = threadIdx.x;
    const int lane = t & 63, wid = t >> 6;
    float4 x = make_float4(0.f,0.f,0.f,0.f);
    if (t < 250) x = *(const float4*)(X + (size_t)row * ND + 4 * t);
    double s = (double)x.x*x.x + (double)x.y*x.y + (double)x.z*x.z + (double)x.w*x.w;
    ushort4 h4, l4;
#pragma unroll
    for (int c = 0; c < 4; ++c){
        float xc = (&x.x)[c];
        ushort h = bf16_rne(xc);
        (&h4.x)[c] = h;
        (&l4.x)[c] = bf16_rne(xc - bf16_to_f(h));
    }
    const int base = (t >> 3) << 5;
    const int grp  = (t >> 1) & 3;
    const int pos  = base + ((grp ^ ((row >> 1) & 3)) << 3) + ((4 * t) & 7);
    *(ushort4*)&H[(size_t)row * KP + pos] = h4;
    *(ushort4*)&L[(size_t)row * KP + pos] = l4;

    __shared__ double pr[4];
    for (int off = 32; off; off >>= 1) s += __shfl_xor(s, off);
    if (lane == 0) pr[wid] = s;
    __syncthreads();
    if (t == 0) sq[row] = (float)(pr[0] + pr[1] + pr[2] + pr[3]);
}

// ---------------- split-bf16 MFMA distance GEMM, global_load_lds staging ----------------
__global__ __launch_bounds__(256) void cn_gemm_dist(){
    __shared__ __attribute__((aligned(16))) ushort Ah[128 * 32];
    __shared__ __attribute__((aligned(16))) ushort Al[128 * 32];
    __shared__ __attribute__((aligned(16))) ushort Bh[128 * 32];
    __shared__ __attribute__((aligned(16))) ushort Bl[128 * 32];

    const int tid = threadIdx.x;
    const int lane = tid & 63, wid = tid >> 6;
    const int wr = wid >> 1, wc = wid & 1;
    const int brow0 = blockIdx.y * 128, bcol0 = blockIdx.x * 128;

    f32x4 acc[4][4];
#pragma unroll
    for (int m = 0; m < 4; ++m)
#pragma unroll
        for (int n = 0; n < 4; ++n) acc[m][n] = (f32x4){0.f,0.f,0.f,0.f};

    const int lrow = lane >> 2;
    const int lcol = (lane & 3) * 8;

    for (int step = 0; step < 32; ++step){
        const int k0 = step * 32;
#pragma unroll
        for (int i = 0; i < 2; ++i){
            const int ch = wid * 2 + i;
            const int ldso = ch * 512;
            const size_t ga = ((size_t)(brow0 + ch * 16 + lrow)) * KP + k0 + lcol;
            const size_t gb = ((size_t)(bcol0 + ch * 16 + lrow)) * KP + k0 + lcol;
            __builtin_amdgcn_global_load_lds((gvoid_t*)(g_Fh + ga), (lvoid_t*)(Ah + ldso), 16, 0, 0);
            __builtin_amdgcn_global_load_lds((gvoid_t*)(g_Fl + ga), (lvoid_t*)(Al + ldso), 16, 0, 0);
            __builtin_amdgcn_global_load_lds((gvoid_t*)(g_Ch + gb), (lvoid_t*)(Bh + ldso), 16, 0, 0);
            __builtin_amdgcn_global_load_lds((gvoid_t*)(g_Cl + gb), (lvoid_t*)(Bl + ldso), 16, 0, 0);
        }
        __syncthreads();

        const int arow = wr * 64 + (lane & 15);
        const int brow = wc * 64 + (lane & 15);
        // swizzled k-group: logical (lane>>4) lives at (lane>>4) ^ ((row>>1)&3);
        // (row>>1)&3 == (lane>>1)&3 for every fragment row we touch.
        const int kof  = (((lane >> 4) ^ ((lane >> 1) & 3)) * 8);
        bf16x8 afh[4], afl[4], bfh[4], bfl[4];
#pragma unroll
        for (int m = 0; m < 4; ++m){
            afh[m] = *(const bf16x8*)&Ah[(arow + m * 16) * 32 + kof];
            afl[m] = *(const bf16x8*)&Al[(arow + m * 16) * 32 + kof];
        }
#pragma unroll
        for (int n = 0; n < 4; ++n){
            bfh[n] = *(const bf16x8*)&Bh[(brow + n * 16) * 32 + kof];
            bfl[n] = *(const bf16x8*)&Bl[(brow + n * 16) * 32 + kof];
        }
#pragma unroll
        for (int m = 0; m < 4; ++m)
#pragma unroll
            for (int n = 0; n < 4; ++n){
                acc[m][n] = __builtin_amdgcn_mfma_f32_16x16x32_bf16(afh[m], bfh[n], acc[m][n], 0, 0, 0);
                acc[m][n] = __builtin_amdgcn_mfma_f32_16x16x32_bf16(afh[m], bfl[n], acc[m][n], 0, 0, 0);
                acc[m][n] = __builtin_amdgcn_mfma_f32_16x16x32_bf16(afl[m], bfh[n], acc[m][n], 0, 0, 0);
            }
        __syncthreads();
    }

#pragma unroll
    for (int m = 0; m < 4; ++m){
        int rowb = brow0 + wr * 64 + m * 16 + (lane >> 4) * 4;
#pragma unroll
        for (int n = 0; n < 4; ++n){
            int col = bcol0 + wc * 64 + n * 16 + (lane & 15);
            float c2v = g_c2[col];
#pragma unroll
            for (int j = 0; j < 4; ++j){
                float d2 = g_f2[rowb + j] + c2v - 2.0f * acc[m][n][j];
                float d  = sqrtf(fmaxf(d2, 0.0f));
                size_t idx = (size_t)(rowb + j) * NK + col;
                g_dist[idx] = d;
                h16 cv; cv.h = (_Float16)(__expf(-2.0f * d) * 8192.0f);
                g_E[idx] = cv.u;
            }
        }
    }
}

// ---------------- fused sinkhorn sweep (+ in-block partial reduction) ----------------
// MODE 0: fp16-e first sweep (u==1):  v = 1/T
// MODE 1: fp16-e mid sweep:           v = (1/B)/T,  T = sum e*u
// MODE 2: fp32 mid sweep (exact tail)
// MODE 3: fp32 final sweep + argmax(2d - ln(uK)), argmin d, bd, histograms
// The fp16 scale (8192) cancels: v absorbs 1/s, u and S are scale-invariant.
template<int MODE>
__global__ __launch_bounds__(256) void cn_sweep(float* __restrict__ outba){
    __shared__ float4 sred[3][8][64];
    const int lane = threadIdx.x & 63, wid = threadIdx.x >> 6;
    const int row0 = (blockIdx.x * 4 + wid) * 4;
    const float cst = (MODE == 0) ? 1.0f : (1.0f / (float)NB);

    float4 uu[8];
    float4 ak[8];
    if (MODE >= 1){
#pragma unroll
        for (int j = 0; j < 8; ++j)
            uu[j] = *(const float4*)&g_u[4 * lane + 256 * j];
    }
    if (MODE == 3){
#pragma unroll
        for (int j = 0; j < 8; ++j)
#pragma unroll
            for (int c = 0; c < 4; ++c)
                (&ak[j].x)[c] = (float)log((double)(&uu[j].x)[c] * (double)NK);
    }

    float4 S[8];
#pragma unroll
    for (int j = 0; j < 8; ++j) S[j] = make_float4(0.f,0.f,0.f,0.f);

    for (int r = 0; r < 4; ++r){
        const int b = row0 + r;
        float4 ev[8];
        float4 dv[8];
        float tsum = 0.f;
        if (MODE <= 1){
            const ushort* er = g_E + (size_t)b * NK + 4 * lane;
#pragma unroll
            for (int j = 0; j < 8; ++j){
                ushort4 q4 = *(const ushort4*)(er + 256 * j);
                float4 e4;
#pragma unroll
                for (int c = 0; c < 4; ++c){
                    h16 cv; cv.u = (&q4.x)[c];
                    float e = (float)cv.h;
                    (&e4.x)[c] = e;
                    tsum += (MODE == 1) ? e * (&uu[j].x)[c] : e;
                }
                ev[j] = e4;
            }
        } else {
            const float* dr = g_dist + (size_t)b * NK + 4 * lane;
#pragma unroll
            for (int j = 0; j < 8; ++j){
                float4 d4 = *(const float4*)(dr + 256 * j);
                float4 e4;
#pragma unroll
                for (int c = 0; c < 4; ++c){
                    float e = __expf(-2.0f * (&d4.x)[c]);
                    (&e4.x)[c] = e;
                    tsum += e * (&uu[j].x)[c];
                }
                ev[j] = e4;
                if (MODE == 3) dv[j] = d4;
            }
        }
#pragma unroll
        for (int off = 32; off; off >>= 1) tsum += __shfl_xor(tsum, off);
        const float v = cst / tsum;
#pragma unroll
        for (int j = 0; j < 8; ++j){
#pragma unroll
            for (int c = 0; c < 4; ++c)
                (&S[j].x)[c] += (&ev[j].x)[c] * v;
        }

        if (MODE == 3){
            double bestT = -1.0e300; int bi = 0; float bd = 0.f;
            float rbest = 3.4e38f;   int ri = 0;
#pragma unroll
            for (int j = 0; j < 8; ++j){
#pragma unroll
                for (int c = 0; c < 4; ++c){
                    int k = 256 * j + 4 * lane + c;
                    float d = (&dv[j].x)[c];
                    double t = 2.0 * (double)d - (double)(&ak[j].x)[c];
                    if (t > bestT){ bestT = t; bi = k; bd = d; }
                    if (d < rbest){ rbest = d; ri = k; }
                }
            }
            for (int off = 32; off; off >>= 1){
                double oT = __shfl_xor(bestT, off);
                int    oi = __shfl_xor(bi, off);
                float  od = __shfl_xor(bd, off);
                if (oT > bestT || (oT == bestT && oi < bi)){ bestT = oT; bi = oi; bd = od; }
                float orb = __shfl_xor(rbest, off);
                int   ori = __shfl_xor(ri, off);
                if (orb < rbest || (orb == rbest && ori < ri)){ rbest = orb; ri = ori; }
            }
            if (lane == 0){
                outba[b] = (float)bi;
                g_bd[b] = bd;
                atomicAdd(&g_cc[bi], 1);
                atomicAdd(&g_rc[ri], 1);
            }
        }
    }

    if (wid > 0){
#pragma unroll
        for (int j = 0; j < 8; ++j) sred[wid - 1][j][lane] = S[j];
    }
    __syncthreads();
    if (wid == 0){
#pragma unroll
        for (int w = 0; w < 3; ++w)
#pragma unroll
            for (int j = 0; j < 8; ++j){
                float4 o = sred[w][j][lane];
                S[j].x += o.x; S[j].y += o.y; S[j].z += o.z; S[j].w += o.w;
            }
#pragma unroll
        for (int j = 0; j < 8; ++j)
            *(float4*)&g_part[(size_t)blockIdx.x * NK + 4 * lane + 256 * j] = S[j];
    }
}

// ---------------- merged partial reduction (fp64, deterministic order) ----------------
// mode 0: u[k] = (1/K)/S_k      mode 1: scnt[k] = B*u[k]*S_k
__global__ __launch_bounds__(256) void cn_red(int mode){
    __shared__ double red[4][64];
    const int lane = threadIdx.x & 63, q = threadIdx.x >> 6;
    const int k = blockIdx.x * 64 + lane;
    double s = 0.0;
    for (int ch = q * 256; ch < q * 256 + 256; ++ch)
        s += (double)g_part[(size_t)ch * NK + k];
    red[q][lane] = s;
    __syncthreads();
    if (q == 0){
        double tot = red[0][lane] + red[1][lane] + red[2][lane] + red[3][lane];
        if (mode == 0) g_u[k] = (float)((1.0 / (double)NK) / tot);
        else           g_scnt[k] = (float)((double)NB * (double)g_u[k] * tot);
    }
}

__global__ __launch_bounds__(256) void cn_zero(){
    int i = blockIdx.x * 256 + threadIdx.x;
    if (i < NK){ g_cc[i] = 0; g_rc[i] = 0; }
}

__global__ __launch_bounds__(256) void cn_finalize(float* __restrict__ out){
    int i = blockIdx.x * 256 + threadIdx.x;
    if (i < NK){
        out[1 + NB + i]            = g_scnt[i];
        out[1 + NB + NK + i]       = (float)g_cc[i];
        out[1 + NB + 2 * NK + i]   = (float)g_rc[i];
    }
    if (blockIdx.x == 0){
        __shared__ double red[4];
        int lane = threadIdx.x & 63, wid = threadIdx.x >> 6;
        double s = 0.0;
        for (int b = threadIdx.x; b < NB; b += 256) s += (double)g_bd[b];
        for (int off = 32; off; off >>= 1) s += __shfl_xor(s, off);
        if (lane == 0) red[wid] = s;
        __syncthreads();
        if (threadIdx.x == 0){
            double tot = red[0] + red[1] + red[2] + red[3];
            out[0] = (float)(tot / (double)NB);
        }
    }
}

extern "C" void kernel_launch(void* const* d_in, const int* in_sizes, int n_in,
                              void* d_out, int out_size, void* d_ws, size_t ws_size,
                              hipStream_t stream){
    const float* F  = (const float*)d_in[0];
    const float* Cn = (const float*)d_in[1];
    float* out = (float*)d_out;
    (void)d_ws; (void)ws_size;

    cn_prep<0><<<NB, 256, 0, stream>>>(F);
    cn_prep<1><<<NK, 256, 0, stream>>>(Cn);
    cn_zero<<<NK / 256, 256, 0, stream>>>();

    dim3 gg(NK / 128, NB / 128);
    cn_gemm_dist<<<gg, 256, 0, stream>>>();

    // sweep 0 (fp16 e): v0 = 1/rowsum, S(v0) -> u_1
    cn_sweep<0><<<NCHK, 256, 0, stream>>>(nullptr);
    cn_red<<<NK / 64, 256, 0, stream>>>(0);

    // sweeps 1..9: fp16 e (u noise ~2e-6, killed by exact tail)
    for (int it = 1; it <= 9; ++it){
        cn_sweep<1><<<NCHK, 256, 0, stream>>>(nullptr);
        cn_red<<<NK / 64, 256, 0, stream>>>(0);
    }
    // sweeps 10..14: exact fp32 (Birkhoff contraction ^5 -> baseline accuracy)
    for (int it = 10; it <= 14; ++it){
        cn_sweep<2><<<NCHK, 256, 0, stream>>>(nullptr);
        cn_red<<<NK / 64, 256, 0, stream>>>(0);
    }

    // final sweep: fused assign/argmin/loss; S(v_15) -> scnt
    cn_sweep<3><<<NCHK, 256, 0, stream>>>(out + 1);
    cn_red<<<NK / 64, 256, 0, stream>>>(1);

    cn_finalize<<<NK / 256, 256, 0, stream>>>(out);
}